// Round 6
// baseline (1252.074 us; speedup 1.0000x reference)
//
#include <hip/hip_runtime.h>
#include <stdint.h>

// MixBlock3D: B=2 C=256 D=8 H=56 W=56, GWS=(2,7,7). I/O f32, intermediates bf16.
// Round 6: LDS-free streaming conv — A and B MFMA fragments loaded directly
// from global (L1/L2) in fragment layout, no barriers in the K-loop.

typedef unsigned short u16;
typedef __attribute__((ext_vector_type(8))) short short8;  // 8 bf16 = 4 VGPR
typedef __attribute__((ext_vector_type(4))) float f32x4;   // 4 fp32 acc

#define TOK   50176
#define CH    256
#define SPAT  25088
#define PLANE 3136

__device__ __forceinline__ float b2f(u16 u) {
    union { uint32_t i; float f; } v; v.i = ((uint32_t)u) << 16; return v.f;
}
__device__ __forceinline__ u16 f2b(float f) {
    union { float f; uint32_t i; } v; v.f = f;
    uint32_t i = v.i;
    uint32_t r = i + 0x7FFFu + ((i >> 16) & 1u);
    return (u16)(r >> 16);
}

// ---------------- LN1: NCDHW f32 -> token-major (t, c) bf16 -----------------
__global__ __launch_bounds__(256) void ln1_kernel(
    const float* __restrict__ x, const float* __restrict__ w,
    const float* __restrict__ bsh, u16* __restrict__ out)
{
    int t = blockIdx.x * 256 + threadIdx.x;
    int b = t / SPAT, sp = t % SPAT;
    const float* px = x + (size_t)b * CH * SPAT + sp;
    float s = 0.f, ss = 0.f;
    for (int c = 0; c < CH; c++) { float v = px[(size_t)c * SPAT]; s += v; ss += v * v; }
    float mean = s * (1.0f / CH);
    float var  = ss * (1.0f / CH) - mean * mean;
    float rstd = rsqrtf(var + 1e-5f);
    u16* po = out + (size_t)t * CH;
    for (int c = 0; c < CH; c++) {
        float v = (px[(size_t)c * SPAT] - mean) * rstd * w[c] + bsh[c];
        po[c] = f2b(v);
    }
}

// ---------------- LN2: token-major bf16 -> token-major bf16 -----------------
__global__ __launch_bounds__(256) void ln2_kernel(
    const u16* __restrict__ x, const float* __restrict__ w,
    const float* __restrict__ bsh, u16* __restrict__ out)
{
    int wave = threadIdx.x >> 6, lane = threadIdx.x & 63;
    int t = blockIdx.x * 4 + wave;
    const u16* px = x + (size_t)t * CH + lane * 4;
    ushort4 v4 = *(const ushort4*)px;
    float v0 = b2f(v4.x), v1 = b2f(v4.y), v2 = b2f(v4.z), v3 = b2f(v4.w);
    float s = v0 + v1 + v2 + v3;
    float ss = v0*v0 + v1*v1 + v2*v2 + v3*v3;
    for (int o = 32; o > 0; o >>= 1) {
        s  += __shfl_xor(s,  o, 64);
        ss += __shfl_xor(ss, o, 64);
    }
    float mean = s * (1.0f / CH);
    float rstd = rsqrtf(ss * (1.0f / CH) - mean * mean + 1e-5f);
    float4 w4 = *(const float4*)(w + lane * 4);
    float4 b4 = *(const float4*)(bsh + lane * 4);
    ushort4 o4;
    o4.x = f2b((v0 - mean) * rstd * w4.x + b4.x);
    o4.y = f2b((v1 - mean) * rstd * w4.y + b4.y);
    o4.z = f2b((v2 - mean) * rstd * w4.z + b4.z);
    o4.w = f2b((v3 - mean) * rstd * w4.w + b4.w);
    *(ushort4*)(out + (size_t)t * CH + lane * 4) = o4;
}

// ---- MFMA GEMM: C[M,Nout slice] = A[M,256](bf16) @ B[N,256]^T(f32 weights) ----
__global__ __launch_bounds__(256) void gemm_mfma_kernel(
    const u16* __restrict__ A, const float* __restrict__ B,
    const float* __restrict__ bias, const u16* __restrict__ res,
    u16* __restrict__ C, int Nout)
{
    __shared__ u16 sAg[128][72];
    __shared__ u16 sBg[128][72];
    int tid = threadIdx.x;
    int m0 = blockIdx.x * 128, n0g = blockIdx.y * 128;
    int lane = tid & 63, wv = tid >> 6;
    int quad = lane >> 4, l15 = lane & 15;
    int mw = (wv & 1) * 64, nw = (wv >> 1) * 64;

    f32x4 zz = {0.f, 0.f, 0.f, 0.f};
    f32x4 acc[4][4];
    #pragma unroll
    for (int i = 0; i < 4; i++)
        #pragma unroll
        for (int j = 0; j < 4; j++) acc[i][j] = zz;

    for (int kc = 0; kc < 256; kc += 64) {
        __syncthreads();
        #pragma unroll
        for (int i = 0; i < 4; i++) {
            int unit = tid + i * 256;
            int row = unit >> 3, k8 = (unit & 7) << 3;
            *(uint4*)&sAg[row][k8] = *(const uint4*)(A + (size_t)(m0 + row) * 256 + kc + k8);
        }
        #pragma unroll
        for (int i = 0; i < 8; i++) {
            int unit = tid + i * 256;
            int row = unit >> 4, k4 = (unit & 15) << 2;
            float4 v = *(const float4*)(B + (size_t)(n0g + row) * 256 + kc + k4);
            ushort4 p;
            p.x = f2b(v.x); p.y = f2b(v.y); p.z = f2b(v.z); p.w = f2b(v.w);
            *(ushort4*)&sBg[row][k4] = p;
        }
        __syncthreads();
        #pragma unroll
        for (int kk = 0; kk < 2; kk++) {
            short8 afr[4], bfr[4];
            #pragma unroll
            for (int mt = 0; mt < 4; mt++)
                afr[mt] = *(const short8*)&sAg[mw + mt*16 + l15][kk*32 + quad*8];
            #pragma unroll
            for (int nt = 0; nt < 4; nt++)
                bfr[nt] = *(const short8*)&sBg[nw + nt*16 + l15][kk*32 + quad*8];
            #pragma unroll
            for (int mt = 0; mt < 4; mt++)
                #pragma unroll
                for (int nt = 0; nt < 4; nt++)
                    acc[mt][nt] = __builtin_amdgcn_mfma_f32_16x16x32_bf16(
                        afr[mt], bfr[nt], acc[mt][nt], 0, 0, 0);
        }
    }

    #pragma unroll
    for (int nt = 0; nt < 4; nt++) {
        int n = n0g + nw + nt*16 + l15;
        float bv = bias ? bias[n] : 0.f;
        #pragma unroll
        for (int mt = 0; mt < 4; mt++) {
            int m = m0 + mw + mt*16 + quad*4;
            #pragma unroll
            for (int r = 0; r < 4; r++) {
                float v = acc[mt][nt][r] + bv;
                size_t off = (size_t)(m + r) * Nout + n;
                if (res) v += b2f(res[off]);
                C[off] = f2b(v);
            }
        }
    }
}

// ---------------- MFMA Attention: one block per (group, head) ---------------
__global__ __launch_bounds__(256) void attn_mfma_kernel(
    const u16* __restrict__ qkv, const float* __restrict__ btab,
    u16* __restrict__ outp, int mode)
{
    __shared__ u16 sKV[8704];        // K [112][72] then V^T [64][136]
    __shared__ u16 sS[112][136];
    __shared__ float sBias[507];
    __shared__ int sTok[112];
    __shared__ int sEnc[112];
    __shared__ float sInv[112];

    int g = blockIdx.x, head = blockIdx.y, tid = threadIdx.x;
    int b  = g >> 8;
    int gd = (g >> 6) & 3, gh = (g >> 3) & 7, gw = g & 7;

    int lane = tid & 63, wv = tid >> 6;
    int quad = lane >> 4, l15 = lane & 15;
    int mts[2] = {wv, wv + 4};

    if (tid < 112) {
        int t = tid;
        int i = t / 49, r = t % 49, j = r / 7, k = r % 7;
        sEnc[tid] = i * 169 + j * 13 + k;
        int tokv = 0;
        if (t < 98) {
            int d, h, w;
            if (mode == 0) { d = gd*2 + i; h = gh*7 + j; w = gw*7 + k; }
            else           { d = i*4 + gd; h = j*8 + gh; w = k*8 + gw; }
            tokv = ((b*8 + d)*56 + h)*56 + w;
        }
        sTok[tid] = tokv;
    }
    for (int idx = tid; idx < 507; idx += 256) sBias[idx] = btab[idx * 4 + head];
    __syncthreads();

    for (int idx = tid; idx < 112 * 8; idx += 256) {
        int row = idx >> 3, c8 = (idx & 7) << 3;
        uint4 v = {0u, 0u, 0u, 0u};
        if (row < 98)
            v = *(const uint4*)(qkv + (size_t)sTok[row] * 768 + 256 + head * 64 + c8);
        *(uint4*)&sKV[row * 72 + c8] = v;
    }
    __syncthreads();

    short8 qf[2][2];
    #pragma unroll
    for (int mi = 0; mi < 2; mi++) {
        int mt = mts[mi];
        #pragma unroll
        for (int ks = 0; ks < 2; ks++) {
            short8 v;
            #pragma unroll
            for (int j = 0; j < 8; j++) v[j] = 0;
            int row = mt * 16 + l15;
            if (mt < 7 && row < 98)
                v = *(const short8*)(qkv + (size_t)sTok[row] * 768 + head * 64 + ks * 32 + quad * 8);
            qf[mi][ks] = v;
        }
    }

    f32x4 zz = {0.f, 0.f, 0.f, 0.f};
    #pragma unroll
    for (int mi = 0; mi < 2; mi++) {
        int mt = mts[mi];
        if (mt >= 7) continue;
        for (int nt = 0; nt < 7; nt++) {
            f32x4 acc = zz;
            acc = __builtin_amdgcn_mfma_f32_16x16x32_bf16(
                qf[mi][0], *(const short8*)&sKV[(nt*16 + l15) * 72 + quad*8], acc, 0, 0, 0);
            acc = __builtin_amdgcn_mfma_f32_16x16x32_bf16(
                qf[mi][1], *(const short8*)&sKV[(nt*16 + l15) * 72 + 32 + quad*8], acc, 0, 0, 0);
            int n = nt * 16 + l15;
            int en = (n < 98) ? sEnc[n] : 0;
            #pragma unroll
            for (int r = 0; r < 4; r++) {
                int m = mt * 16 + quad * 4 + r;
                float v;
                if (n < 98) {
                    int em = sEnc[m < 98 ? m : 97];
                    v = acc[r] * 0.125f + sBias[em - en + 253];
                } else v = -1e30f;
                sS[m][n] = f2b(v);
            }
        }
    }
    __syncthreads();

    for (int idx = tid; idx < 64 * 30; idx += 256) {
        int c = idx / 30, t = 98 + idx % 30;
        sKV[c * 136 + t] = 0;
    }
    for (int idx = tid; idx < 98 * 8; idx += 256) {
        int tok = idx >> 3, c8 = (idx & 7) << 3;
        uint4 v = *(const uint4*)(qkv + (size_t)sTok[tok] * 768 + 512 + head * 64 + c8);
        const u16* pv = (const u16*)&v;
        #pragma unroll
        for (int j = 0; j < 8; j++) sKV[(c8 + j) * 136 + tok] = pv[j];
    }

    {
        int row = tid >> 1, half = tid & 1;
        if (row < 112) {
            #pragma unroll
            for (int j = 0; j < 8; j++) sS[row][112 + half * 8 + j] = 0;
        }
        if (row < 98) {
            int c0 = half * 49;
            float mx = -1e30f;
            for (int j = 0; j < 49; j++) mx = fmaxf(mx, b2f(sS[row][c0 + j]));
            mx = fmaxf(mx, __shfl_xor(mx, 1, 64));
            float sum = 0.f;
            for (int j = 0; j < 49; j++) {
                float e = __expf(b2f(sS[row][c0 + j]) - mx);
                sum += e;
                sS[row][c0 + j] = f2b(e);
            }
            sum += __shfl_xor(sum, 1, 64);
            if (half == 0) sInv[row] = 1.0f / sum;
        }
    }
    __syncthreads();

    f32x4 po[2][4];
    #pragma unroll
    for (int mi = 0; mi < 2; mi++)
        #pragma unroll
        for (int nt = 0; nt < 4; nt++) po[mi][nt] = zz;

    #pragma unroll
    for (int mi = 0; mi < 2; mi++) {
        int mt = mts[mi];
        if (mt >= 7) continue;
        for (int ks = 0; ks < 4; ks++) {
            short8 ap = *(const short8*)&sS[mt*16 + l15][ks*32 + quad*8];
            #pragma unroll
            for (int nt = 0; nt < 4; nt++) {
                short8 bv = *(const short8*)&sKV[(nt*16 + l15) * 136 + ks*32 + quad*8];
                po[mi][nt] = __builtin_amdgcn_mfma_f32_16x16x32_bf16(ap, bv, po[mi][nt], 0, 0, 0);
            }
        }
    }

    #pragma unroll
    for (int mi = 0; mi < 2; mi++) {
        int mt = mts[mi];
        if (mt >= 7) continue;
        #pragma unroll
        for (int r = 0; r < 4; r++) {
            int m = mt * 16 + quad * 4 + r;
            if (m >= 98) continue;
            float inv = sInv[m];
            u16* dst = outp + (size_t)sTok[m] * 256 + head * 64 + l15;
            #pragma unroll
            for (int nt = 0; nt < 4; nt++)
                dst[nt * 16] = f2b(po[mi][nt][r] * inv);
        }
    }
}

// ---- s = input(f32 NCDHW) + y(bf16 token-major) -> s1/s2 channel-last bf16 --
__global__ __launch_bounds__(256) void ssplit_cl_kernel(
    const float* __restrict__ inp, const u16* __restrict__ y,
    u16* __restrict__ s1, u16* __restrict__ s2)
{
    __shared__ float sT[64][65];
    int t0 = blockIdx.x * 64;
    int b = t0 / SPAT, sp0 = t0 % SPAT;
    int tid = threadIdx.x;
    for (int cg = 0; cg < 4; cg++) {
        __syncthreads();
        #pragma unroll
        for (int i = 0; i < 16; i++) {
            int unit = tid + i * 256;
            int cl = unit >> 6, spl = unit & 63;
            sT[spl][cl] = inp[((size_t)(b * 256 + cg * 64 + cl)) * SPAT + sp0 + spl];
        }
        __syncthreads();
        int spl = tid >> 2, c16 = (tid & 3) * 16;
        int tok = t0 + spl;
        const u16* yp = y + (size_t)tok * 256 + cg * 64 + c16;
        int cbase = cg * 64 + c16;
        u16* dst = (cbase < 128) ? (s1 + (size_t)tok * 128 + cbase)
                                 : (s2 + (size_t)tok * 128 + cbase - 128);
        #pragma unroll
        for (int j = 0; j < 16; j++) {
            float v = sT[spl][c16 + j] + b2f(yp[j]);
            dst[j] = f2b(v);
        }
    }
}

// ---- conv weight transform: f32 [oc][ic][27] -> bf16 [27][oc][ic] ----------
__global__ __launch_bounds__(256) void convw_kernel(
    const float* __restrict__ w, u16* __restrict__ o)
{
    int e = blockIdx.x * 256 + threadIdx.x;
    int k = e >> 14;
    int r = e & 16383;
    o[e] = f2b(w[(size_t)r * 27 + k]);
}

// ---- LDS-free streaming MFMA conv 3x3x3 128->128, channel-last -------------
// 128 threads = 2 waves; wave wv: 64 tokens x 64 oc (oc half wv*64).
// A and B fragments loaded directly from global in fragment layout.
// No barriers in the K-loop. Dynamic LDS only for the f32-NCDHW epilogue.
extern __shared__ float conv_smem[];   // [128][67] f32 when out_f32 != null
__global__ __launch_bounds__(128, 3) void conv_mfma_kernel(
    const u16* __restrict__ in_cl,   // [B*SPAT][128] bf16
    const u16* __restrict__ wt27,    // [27][128 oc][128 ic] bf16
    const float* __restrict__ bias,  // [128] f32
    const u16* __restrict__ res_cl,  // nullable [tok][128] bf16 (added to acc)
    u16* __restrict__ out_cl,        // nullable [tok][128] bf16
    float* __restrict__ out_f32,     // nullable NCDHW f32 (256-ch layout)
    int oc_base, int leaky)
{
    int tid = threadIdx.x;
    int t0 = blockIdx.x * 64;
    int b = t0 / SPAT, sp0 = t0 % SPAT;
    int lane = tid & 63, wv = tid >> 6;
    int quad = lane >> 4, l15 = lane & 15;
    int nw = wv * 64;

    // per-lane token coords + channel-row base for the 4 M tiles
    int dm[4], hm[4], wm[4];
    const u16* abase[4];
    #pragma unroll
    for (int mt = 0; mt < 4; mt++) {
        int sp = sp0 + mt*16 + l15;
        dm[mt] = sp / PLANE;
        int r = sp % PLANE;
        hm[mt] = r / 56; wm[mt] = r % 56;
        abase[mt] = in_cl + ((size_t)b * SPAT + sp) * 128 + quad * 8;
    }
    // per-lane weight offsets for the 4 N tiles
    int boff[4];
    #pragma unroll
    for (int nt = 0; nt < 4; nt++)
        boff[nt] = (nw + nt*16 + l15) * 128 + quad * 8;

    f32x4 zz = {0.f, 0.f, 0.f, 0.f};
    f32x4 acc[4][4];
    #pragma unroll
    for (int i = 0; i < 4; i++)
        #pragma unroll
        for (int j = 0; j < 4; j++) acc[i][j] = zz;

    short8 z8;
    #pragma unroll
    for (int j = 0; j < 8; j++) z8[j] = 0;

    for (int ko = 0; ko < 27; ko++) {
        int kd = ko / 9 - 1, kh = (ko / 3) % 3 - 1, kw = ko % 3 - 1;
        int soff = (kd * PLANE + kh * 56 + kw) * 128;   // element offset
        const u16* wbase = wt27 + ko * 16384;
        bool val[4];
        #pragma unroll
        for (int mt = 0; mt < 4; mt++)
            val[mt] = (unsigned)(dm[mt] + kd) < 8u &&
                      (unsigned)(hm[mt] + kh) < 56u &&
                      (unsigned)(wm[mt] + kw) < 56u;
        #pragma unroll
        for (int kk = 0; kk < 4; kk++) {
            short8 afr[4], bfr[4];
            #pragma unroll
            for (int mt = 0; mt < 4; mt++)
                afr[mt] = val[mt] ? *(const short8*)(abase[mt] + soff + kk*32) : z8;
            #pragma unroll
            for (int nt = 0; nt < 4; nt++)
                bfr[nt] = *(const short8*)(wbase + boff[nt] + kk*32);
            #pragma unroll
            for (int mt = 0; mt < 4; mt++)
                #pragma unroll
                for (int nt = 0; nt < 4; nt++)
                    acc[mt][nt] = __builtin_amdgcn_mfma_f32_16x16x32_bf16(
                        afr[mt], bfr[nt], acc[mt][nt], 0, 0, 0);
        }
    }

    // bias + leaky + residual (into ACC so both outputs get it)
    #pragma unroll
    for (int nt = 0; nt < 4; nt++) {
        int oc = nw + nt*16 + l15;
        float bv = bias[oc];
        #pragma unroll
        for (int mt = 0; mt < 4; mt++) {
            int m = mt*16 + quad*4;
            #pragma unroll
            for (int r = 0; r < 4; r++) {
                float v = acc[mt][nt][r] + bv;
                if (leaky) v = (v >= 0.f) ? v : 0.01f * v;
                if (res_cl) v += b2f(res_cl[(size_t)(t0 + m + r) * 128 + oc]);
                acc[mt][nt][r] = v;
            }
        }
    }

    if (out_cl) {
        #pragma unroll
        for (int mt = 0; mt < 4; mt++) {
            int m = mt*16 + quad*4;
            #pragma unroll
            for (int nt = 0; nt < 4; nt++) {
                int oc = nw + nt*16 + l15;
                #pragma unroll
                for (int r = 0; r < 4; r++)
                    out_cl[(size_t)(t0 + m + r) * 128 + oc] = f2b(acc[mt][nt][r]);
            }
        }
    }

    if (out_f32) {
        float* sT = conv_smem;   // [128][67]
        #pragma unroll
        for (int mt = 0; mt < 4; mt++) {
            int m = mt*16 + quad*4;
            #pragma unroll
            for (int nt = 0; nt < 4; nt++) {
                int oc = nw + nt*16 + l15;
                #pragma unroll
                for (int r = 0; r < 4; r++)
                    sT[oc * 67 + m + r] = acc[mt][nt][r];
            }
        }
        __syncthreads();
        int oc = tid;            // 128 threads = 128 oc
        float* dst = out_f32 + ((size_t)b * 256 + oc_base + oc) * SPAT + sp0;
        const float* row = &sT[oc * 67];
        #pragma unroll
        for (int j = 0; j < 16; j++) {
            float4 v = { row[j*4+0], row[j*4+1], row[j*4+2], row[j*4+3] };
            *(float4*)(dst + j*4) = v;
        }
    }
}

// ---------------- launch ----------------------------------------------------
extern "C" void kernel_launch(void* const* d_in, const int* in_sizes, int n_in,
                              void* d_out, int out_size, void* d_ws, size_t ws_size,
                              hipStream_t stream)
{
    const float* input  = (const float*)d_in[0];
    const float* n1w    = (const float*)d_in[1];
    const float* n1b    = (const float*)d_in[2];
    const float* n2w    = (const float*)d_in[3];
    const float* n2b    = (const float*)d_in[4];
    const float* wqkv   = (const float*)d_in[5];
    const float* wprojw = (const float*)d_in[6];
    const float* wprojb = (const float*)d_in[7];
    const float* wbias  = (const float*)d_in[8];
    const float* gqkv   = (const float*)d_in[9];
    const float* gprojw = (const float*)d_in[10];
    const float* gprojb = (const float*)d_in[11];
    const float* gbias  = (const float*)d_in[12];
    const float* f1c1w  = (const float*)d_in[13];
    const float* f1c1b  = (const float*)d_in[14];
    const float* f1c2w  = (const float*)d_in[15];
    const float* f1c2b  = (const float*)d_in[16];
    const float* g1c1w  = (const float*)d_in[17];
    const float* g1c1b  = (const float*)d_in[18];
    const float* g1c2w  = (const float*)d_in[19];
    const float* g1c2b  = (const float*)d_in[20];

    char* ws = (char*)d_ws;
    u16* xln   = (u16*)(ws);                    // 25,690,112 B (later: y)
    u16* qkv   = (u16*)(ws + 25690112);         // 77,070,336 B (later: conv bufs)
    u16* attnb = (u16*)(ws + 102760448);        // 25,690,112 B
    u16* xw    = (u16*)(ws + 128450560);        // 25,690,112 B
    u16* y  = xln;
    u16* s1   = qkv;
    u16* s2   = (u16*)(ws + 25690112 + 12845056);
    u16* tb   = (u16*)(ws + 25690112 + 25690112);
    u16* y1cl = (u16*)(ws + 25690112 + 38535168);
    u16* cw0  = (u16*)(ws + 25690112 + 51380224);
    u16* cw1  = cw0 + 442368;
    u16* cw2  = cw1 + 442368;
    u16* cw3  = cw2 + 442368;

    float* outp = (float*)d_out;
    const int F32_LDS = 128 * 67 * 4;   // 34,304 B dynamic LDS for f32 epilogue

    // 1) LN1
    ln1_kernel<<<196, 256, 0, stream>>>(input, n1w, n1b, xln);
    // 2) window qkv
    gemm_mfma_kernel<<<dim3(392, 6), 256, 0, stream>>>(xln, wqkv, nullptr, nullptr, qkv, 768);
    // 3) window attention (MFMA)
    attn_mfma_kernel<<<dim3(512, 4), 256, 0, stream>>>(qkv, wbias, attnb, 0);
    // 4) window proj -> xw
    gemm_mfma_kernel<<<dim3(392, 2), 256, 0, stream>>>(attnb, wprojw, wprojb, nullptr, xw, 256);
    // 5) LN2 -> xln
    ln2_kernel<<<12544, 256, 0, stream>>>(xw, n2w, n2b, xln);
    // 6) grid qkv
    gemm_mfma_kernel<<<dim3(392, 6), 256, 0, stream>>>(xln, gqkv, nullptr, nullptr, qkv, 768);
    // 7) grid attention (MFMA)
    attn_mfma_kernel<<<dim3(512, 4), 256, 0, stream>>>(qkv, gbias, attnb, 1);
    // 8) grid proj + xw residual -> y
    gemm_mfma_kernel<<<dim3(392, 2), 256, 0, stream>>>(attnb, gprojw, gprojb, xw, y, 256);
    // 9) s = input + y -> channel-last halves
    ssplit_cl_kernel<<<784, 256, 0, stream>>>(input, y, s1, s2);
    // 10) conv weight transforms
    convw_kernel<<<1728, 256, 0, stream>>>(f1c1w, cw0);
    convw_kernel<<<1728, 256, 0, stream>>>(f1c2w, cw1);
    convw_kernel<<<1728, 256, 0, stream>>>(g1c1w, cw2);
    convw_kernel<<<1728, 256, 0, stream>>>(g1c2w, cw3);
    // 11) t = leaky(conv(s2, f1c1))
    conv_mfma_kernel<<<784, 128, 0, stream>>>(s2, cw0, f1c1b, nullptr, tb, nullptr, 0, 1);
    // 12) y1 = s1 + conv(t, f1c2) -> d_out[:,0:128] and y1cl
    conv_mfma_kernel<<<784, 128, F32_LDS, stream>>>(tb, cw1, f1c2b, s1, y1cl, outp, 0, 0);
    // 13) t = leaky(conv(y1, g1c1))
    conv_mfma_kernel<<<784, 128, 0, stream>>>(y1cl, cw2, g1c1b, nullptr, tb, nullptr, 0, 1);
    // 14) y2 = s2 + conv(t, g1c2) -> d_out[:,128:256]
    conv_mfma_kernel<<<784, 128, F32_LDS, stream>>>(tb, cw3, g1c2b, s2, nullptr, outp, 128, 0);
}

// Round 7
// 971.488 us; speedup vs baseline: 1.2888x; 1.2888x over previous
//
#include <hip/hip_runtime.h>
#include <stdint.h>

// MixBlock3D: B=2 C=256 D=8 H=56 W=56, GWS=(2,7,7). I/O f32, intermediates bf16.
// Round 7: conv back to LDS staging (R5 shape) but with FRAGMENT-LINEAR LDS
// layout [kk][row][quad*8] -> conflict-free ds_read_b128 / inherent-rate writes.

typedef unsigned short u16;
typedef __attribute__((ext_vector_type(8))) short short8;  // 8 bf16 = 4 VGPR
typedef __attribute__((ext_vector_type(4))) float f32x4;   // 4 fp32 acc

#define TOK   50176
#define CH    256
#define SPAT  25088
#define PLANE 3136

__device__ __forceinline__ float b2f(u16 u) {
    union { uint32_t i; float f; } v; v.i = ((uint32_t)u) << 16; return v.f;
}
__device__ __forceinline__ u16 f2b(float f) {
    union { float f; uint32_t i; } v; v.f = f;
    uint32_t i = v.i;
    uint32_t r = i + 0x7FFFu + ((i >> 16) & 1u);
    return (u16)(r >> 16);
}

// ---------------- LN1: NCDHW f32 -> token-major (t, c) bf16 -----------------
__global__ __launch_bounds__(256) void ln1_kernel(
    const float* __restrict__ x, const float* __restrict__ w,
    const float* __restrict__ bsh, u16* __restrict__ out)
{
    int t = blockIdx.x * 256 + threadIdx.x;
    int b = t / SPAT, sp = t % SPAT;
    const float* px = x + (size_t)b * CH * SPAT + sp;
    float s = 0.f, ss = 0.f;
    for (int c = 0; c < CH; c++) { float v = px[(size_t)c * SPAT]; s += v; ss += v * v; }
    float mean = s * (1.0f / CH);
    float var  = ss * (1.0f / CH) - mean * mean;
    float rstd = rsqrtf(var + 1e-5f);
    u16* po = out + (size_t)t * CH;
    for (int c = 0; c < CH; c++) {
        float v = (px[(size_t)c * SPAT] - mean) * rstd * w[c] + bsh[c];
        po[c] = f2b(v);
    }
}

// ---------------- LN2: token-major bf16 -> token-major bf16 -----------------
__global__ __launch_bounds__(256) void ln2_kernel(
    const u16* __restrict__ x, const float* __restrict__ w,
    const float* __restrict__ bsh, u16* __restrict__ out)
{
    int wave = threadIdx.x >> 6, lane = threadIdx.x & 63;
    int t = blockIdx.x * 4 + wave;
    const u16* px = x + (size_t)t * CH + lane * 4;
    ushort4 v4 = *(const ushort4*)px;
    float v0 = b2f(v4.x), v1 = b2f(v4.y), v2 = b2f(v4.z), v3 = b2f(v4.w);
    float s = v0 + v1 + v2 + v3;
    float ss = v0*v0 + v1*v1 + v2*v2 + v3*v3;
    for (int o = 32; o > 0; o >>= 1) {
        s  += __shfl_xor(s,  o, 64);
        ss += __shfl_xor(ss, o, 64);
    }
    float mean = s * (1.0f / CH);
    float rstd = rsqrtf(ss * (1.0f / CH) - mean * mean + 1e-5f);
    float4 w4 = *(const float4*)(w + lane * 4);
    float4 b4 = *(const float4*)(bsh + lane * 4);
    ushort4 o4;
    o4.x = f2b((v0 - mean) * rstd * w4.x + b4.x);
    o4.y = f2b((v1 - mean) * rstd * w4.y + b4.y);
    o4.z = f2b((v2 - mean) * rstd * w4.z + b4.z);
    o4.w = f2b((v3 - mean) * rstd * w4.w + b4.w);
    *(ushort4*)(out + (size_t)t * CH + lane * 4) = o4;
}

// ---- MFMA GEMM: C[M,Nout slice] = A[M,256](bf16) @ B[N,256]^T(f32 weights) ----
__global__ __launch_bounds__(256) void gemm_mfma_kernel(
    const u16* __restrict__ A, const float* __restrict__ B,
    const float* __restrict__ bias, const u16* __restrict__ res,
    u16* __restrict__ C, int Nout)
{
    __shared__ u16 sAg[128][72];
    __shared__ u16 sBg[128][72];
    int tid = threadIdx.x;
    int m0 = blockIdx.x * 128, n0g = blockIdx.y * 128;
    int lane = tid & 63, wv = tid >> 6;
    int quad = lane >> 4, l15 = lane & 15;
    int mw = (wv & 1) * 64, nw = (wv >> 1) * 64;

    f32x4 zz = {0.f, 0.f, 0.f, 0.f};
    f32x4 acc[4][4];
    #pragma unroll
    for (int i = 0; i < 4; i++)
        #pragma unroll
        for (int j = 0; j < 4; j++) acc[i][j] = zz;

    for (int kc = 0; kc < 256; kc += 64) {
        __syncthreads();
        #pragma unroll
        for (int i = 0; i < 4; i++) {
            int unit = tid + i * 256;
            int row = unit >> 3, k8 = (unit & 7) << 3;
            *(uint4*)&sAg[row][k8] = *(const uint4*)(A + (size_t)(m0 + row) * 256 + kc + k8);
        }
        #pragma unroll
        for (int i = 0; i < 8; i++) {
            int unit = tid + i * 256;
            int row = unit >> 4, k4 = (unit & 15) << 2;
            float4 v = *(const float4*)(B + (size_t)(n0g + row) * 256 + kc + k4);
            ushort4 p;
            p.x = f2b(v.x); p.y = f2b(v.y); p.z = f2b(v.z); p.w = f2b(v.w);
            *(ushort4*)&sBg[row][k4] = p;
        }
        __syncthreads();
        #pragma unroll
        for (int kk = 0; kk < 2; kk++) {
            short8 afr[4], bfr[4];
            #pragma unroll
            for (int mt = 0; mt < 4; mt++)
                afr[mt] = *(const short8*)&sAg[mw + mt*16 + l15][kk*32 + quad*8];
            #pragma unroll
            for (int nt = 0; nt < 4; nt++)
                bfr[nt] = *(const short8*)&sBg[nw + nt*16 + l15][kk*32 + quad*8];
            #pragma unroll
            for (int mt = 0; mt < 4; mt++)
                #pragma unroll
                for (int nt = 0; nt < 4; nt++)
                    acc[mt][nt] = __builtin_amdgcn_mfma_f32_16x16x32_bf16(
                        afr[mt], bfr[nt], acc[mt][nt], 0, 0, 0);
        }
    }

    #pragma unroll
    for (int nt = 0; nt < 4; nt++) {
        int n = n0g + nw + nt*16 + l15;
        float bv = bias ? bias[n] : 0.f;
        #pragma unroll
        for (int mt = 0; mt < 4; mt++) {
            int m = m0 + mw + mt*16 + quad*4;
            #pragma unroll
            for (int r = 0; r < 4; r++) {
                float v = acc[mt][nt][r] + bv;
                size_t off = (size_t)(m + r) * Nout + n;
                if (res) v += b2f(res[off]);
                C[off] = f2b(v);
            }
        }
    }
}

// ---------------- MFMA Attention: one block per (group, head) ---------------
__global__ __launch_bounds__(256) void attn_mfma_kernel(
    const u16* __restrict__ qkv, const float* __restrict__ btab,
    u16* __restrict__ outp, int mode)
{
    __shared__ u16 sKV[8704];        // K [112][72] then V^T [64][136]
    __shared__ u16 sS[112][136];
    __shared__ float sBias[507];
    __shared__ int sTok[112];
    __shared__ int sEnc[112];
    __shared__ float sInv[112];

    int g = blockIdx.x, head = blockIdx.y, tid = threadIdx.x;
    int b  = g >> 8;
    int gd = (g >> 6) & 3, gh = (g >> 3) & 7, gw = g & 7;

    int lane = tid & 63, wv = tid >> 6;
    int quad = lane >> 4, l15 = lane & 15;
    int mts[2] = {wv, wv + 4};

    if (tid < 112) {
        int t = tid;
        int i = t / 49, r = t % 49, j = r / 7, k = r % 7;
        sEnc[tid] = i * 169 + j * 13 + k;
        int tokv = 0;
        if (t < 98) {
            int d, h, w;
            if (mode == 0) { d = gd*2 + i; h = gh*7 + j; w = gw*7 + k; }
            else           { d = i*4 + gd; h = j*8 + gh; w = k*8 + gw; }
            tokv = ((b*8 + d)*56 + h)*56 + w;
        }
        sTok[tid] = tokv;
    }
    for (int idx = tid; idx < 507; idx += 256) sBias[idx] = btab[idx * 4 + head];
    __syncthreads();

    for (int idx = tid; idx < 112 * 8; idx += 256) {
        int row = idx >> 3, c8 = (idx & 7) << 3;
        uint4 v = {0u, 0u, 0u, 0u};
        if (row < 98)
            v = *(const uint4*)(qkv + (size_t)sTok[row] * 768 + 256 + head * 64 + c8);
        *(uint4*)&sKV[row * 72 + c8] = v;
    }
    __syncthreads();

    short8 qf[2][2];
    #pragma unroll
    for (int mi = 0; mi < 2; mi++) {
        int mt = mts[mi];
        #pragma unroll
        for (int ks = 0; ks < 2; ks++) {
            short8 v;
            #pragma unroll
            for (int j = 0; j < 8; j++) v[j] = 0;
            int row = mt * 16 + l15;
            if (mt < 7 && row < 98)
                v = *(const short8*)(qkv + (size_t)sTok[row] * 768 + head * 64 + ks * 32 + quad * 8);
            qf[mi][ks] = v;
        }
    }

    f32x4 zz = {0.f, 0.f, 0.f, 0.f};
    #pragma unroll
    for (int mi = 0; mi < 2; mi++) {
        int mt = mts[mi];
        if (mt >= 7) continue;
        for (int nt = 0; nt < 7; nt++) {
            f32x4 acc = zz;
            acc = __builtin_amdgcn_mfma_f32_16x16x32_bf16(
                qf[mi][0], *(const short8*)&sKV[(nt*16 + l15) * 72 + quad*8], acc, 0, 0, 0);
            acc = __builtin_amdgcn_mfma_f32_16x16x32_bf16(
                qf[mi][1], *(const short8*)&sKV[(nt*16 + l15) * 72 + 32 + quad*8], acc, 0, 0, 0);
            int n = nt * 16 + l15;
            int en = (n < 98) ? sEnc[n] : 0;
            #pragma unroll
            for (int r = 0; r < 4; r++) {
                int m = mt * 16 + quad * 4 + r;
                float v;
                if (n < 98) {
                    int em = sEnc[m < 98 ? m : 97];
                    v = acc[r] * 0.125f + sBias[em - en + 253];
                } else v = -1e30f;
                sS[m][n] = f2b(v);
            }
        }
    }
    __syncthreads();

    for (int idx = tid; idx < 64 * 30; idx += 256) {
        int c = idx / 30, t = 98 + idx % 30;
        sKV[c * 136 + t] = 0;
    }
    for (int idx = tid; idx < 98 * 8; idx += 256) {
        int tok = idx >> 3, c8 = (idx & 7) << 3;
        uint4 v = *(const uint4*)(qkv + (size_t)sTok[tok] * 768 + 512 + head * 64 + c8);
        const u16* pv = (const u16*)&v;
        #pragma unroll
        for (int j = 0; j < 8; j++) sKV[(c8 + j) * 136 + tok] = pv[j];
    }

    {
        int row = tid >> 1, half = tid & 1;
        if (row < 112) {
            #pragma unroll
            for (int j = 0; j < 8; j++) sS[row][112 + half * 8 + j] = 0;
        }
        if (row < 98) {
            int c0 = half * 49;
            float mx = -1e30f;
            for (int j = 0; j < 49; j++) mx = fmaxf(mx, b2f(sS[row][c0 + j]));
            mx = fmaxf(mx, __shfl_xor(mx, 1, 64));
            float sum = 0.f;
            for (int j = 0; j < 49; j++) {
                float e = __expf(b2f(sS[row][c0 + j]) - mx);
                sum += e;
                sS[row][c0 + j] = f2b(e);
            }
            sum += __shfl_xor(sum, 1, 64);
            if (half == 0) sInv[row] = 1.0f / sum;
        }
    }
    __syncthreads();

    f32x4 po[2][4];
    #pragma unroll
    for (int mi = 0; mi < 2; mi++)
        #pragma unroll
        for (int nt = 0; nt < 4; nt++) po[mi][nt] = zz;

    #pragma unroll
    for (int mi = 0; mi < 2; mi++) {
        int mt = mts[mi];
        if (mt >= 7) continue;
        for (int ks = 0; ks < 4; ks++) {
            short8 ap = *(const short8*)&sS[mt*16 + l15][ks*32 + quad*8];
            #pragma unroll
            for (int nt = 0; nt < 4; nt++) {
                short8 bv = *(const short8*)&sKV[(nt*16 + l15) * 136 + ks*32 + quad*8];
                po[mi][nt] = __builtin_amdgcn_mfma_f32_16x16x32_bf16(ap, bv, po[mi][nt], 0, 0, 0);
            }
        }
    }

    #pragma unroll
    for (int mi = 0; mi < 2; mi++) {
        int mt = mts[mi];
        if (mt >= 7) continue;
        #pragma unroll
        for (int r = 0; r < 4; r++) {
            int m = mt * 16 + quad * 4 + r;
            if (m >= 98) continue;
            float inv = sInv[m];
            u16* dst = outp + (size_t)sTok[m] * 256 + head * 64 + l15;
            #pragma unroll
            for (int nt = 0; nt < 4; nt++)
                dst[nt * 16] = f2b(po[mi][nt][r] * inv);
        }
    }
}

// ---- s = input(f32 NCDHW) + y(bf16 token-major) -> s1/s2 channel-last bf16 --
__global__ __launch_bounds__(256) void ssplit_cl_kernel(
    const float* __restrict__ inp, const u16* __restrict__ y,
    u16* __restrict__ s1, u16* __restrict__ s2)
{
    __shared__ float sT[64][65];
    int t0 = blockIdx.x * 64;
    int b = t0 / SPAT, sp0 = t0 % SPAT;
    int tid = threadIdx.x;
    for (int cg = 0; cg < 4; cg++) {
        __syncthreads();
        #pragma unroll
        for (int i = 0; i < 16; i++) {
            int unit = tid + i * 256;
            int cl = unit >> 6, spl = unit & 63;
            sT[spl][cl] = inp[((size_t)(b * 256 + cg * 64 + cl)) * SPAT + sp0 + spl];
        }
        __syncthreads();
        int spl = tid >> 2, c16 = (tid & 3) * 16;
        int tok = t0 + spl;
        const u16* yp = y + (size_t)tok * 256 + cg * 64 + c16;
        int cbase = cg * 64 + c16;
        u16* dst = (cbase < 128) ? (s1 + (size_t)tok * 128 + cbase)
                                 : (s2 + (size_t)tok * 128 + cbase - 128);
        #pragma unroll
        for (int j = 0; j < 16; j++) {
            float v = sT[spl][c16 + j] + b2f(yp[j]);
            dst[j] = f2b(v);
        }
    }
}

// ---- conv weight transform: f32 [oc][ic][27] -> bf16 [27][oc][ic] ----------
__global__ __launch_bounds__(256) void convw_kernel(
    const float* __restrict__ w, u16* __restrict__ o)
{
    int e = blockIdx.x * 256 + threadIdx.x;
    int k = e >> 14;
    int r = e & 16383;
    o[e] = f2b(w[(size_t)r * 27 + k]);
}

// ---- MFMA conv 3x3x3 128->128, implicit GEMM, fragment-linear LDS ----------
// block: 64 tokens x 128 oc, 4 waves (wave = 64 tok x 32 oc slice).
// LDS layout [kk][row][quad*8] -> ds_read_b128 conflict-free.
__global__ __launch_bounds__(256) void conv_mfma_kernel(
    const u16* __restrict__ in_cl,   // [B*SPAT][128] bf16
    const u16* __restrict__ wt27,    // [27][128 oc][128 ic] bf16
    const float* __restrict__ bias,  // [128] f32
    const u16* __restrict__ res_cl,  // nullable [tok][128] bf16 (added to acc)
    u16* __restrict__ out_cl,        // nullable [tok][128] bf16
    float* __restrict__ out_f32,     // nullable NCDHW f32 (256-ch layout)
    int oc_base, int leaky)
{
    __shared__ u16 sA[8192];         // [kk4][m64][32]  = 16,384 B
    __shared__ u16 sB[16640];        // [kk4][oc128][32] = 32,768 B (+512 B for f32 epi)
    __shared__ int sD[64], sHH[64], sWW[64];

    int tid = threadIdx.x;
    int t0 = blockIdx.x * 64;
    int b = t0 / SPAT, sp0 = t0 % SPAT;

    if (tid < 64) {
        int sp = sp0 + tid;
        int d = sp / PLANE, r = sp % PLANE;
        sD[tid] = d; sHH[tid] = r / 56; sWW[tid] = r % 56;
    }

    int lane = tid & 63, wv = tid >> 6;
    int quad = lane >> 4, l15 = lane & 15;
    int n0 = wv * 32;

    f32x4 zz = {0.f, 0.f, 0.f, 0.f};
    f32x4 acc[4][2];
    #pragma unroll
    for (int i = 0; i < 4; i++) { acc[i][0] = zz; acc[i][1] = zz; }

    __syncthreads();

    for (int ko = 0; ko < 27; ko++) {
        int kd = ko / 9 - 1, kh = (ko / 3) % 3 - 1, kw = ko % 3 - 1;
        __syncthreads();
        // stage A: 64 tokens x 128 ic, fragment-linear [kk][m][quad*8]
        #pragma unroll
        for (int i = 0; i < 4; i++) {
            int unit = tid + i * 256;
            int m = unit >> 4, u = unit & 15;      // u: kk = u>>2, q = u&3
            int dd = sD[m] + kd, hh = sHH[m] + kh, ww = sWW[m] + kw;
            uint4 v = {0u, 0u, 0u, 0u};
            if ((unsigned)dd < 8u && (unsigned)hh < 56u && (unsigned)ww < 56u) {
                size_t sp = (size_t)(b * 8 + dd) * PLANE + hh * 56 + ww;
                v = *(const uint4*)(in_cl + sp * 128 + u * 8);
            }
            *(uint4*)&sA[(u >> 2) * 2048 + m * 32 + (u & 3) * 8] = v;
        }
        // stage W tap slice: 128 oc x 128 ic, fragment-linear [kk][oc][quad*8]
        const u16* wp = wt27 + (size_t)ko * 16384;
        #pragma unroll
        for (int i = 0; i < 8; i++) {
            int unit = tid + i * 256;
            int oc = unit >> 4, u = unit & 15;
            *(uint4*)&sB[(u >> 2) * 4096 + oc * 32 + (u & 3) * 8] =
                *(const uint4*)(wp + oc * 128 + u * 8);
        }
        __syncthreads();
        #pragma unroll
        for (int kk = 0; kk < 4; kk++) {
            short8 afr[4], bfr[2];
            #pragma unroll
            for (int mt = 0; mt < 4; mt++)
                afr[mt] = *(const short8*)&sA[kk*2048 + (mt*16 + l15)*32 + quad*8];
            #pragma unroll
            for (int nt = 0; nt < 2; nt++)
                bfr[nt] = *(const short8*)&sB[kk*4096 + (n0 + nt*16 + l15)*32 + quad*8];
            #pragma unroll
            for (int mt = 0; mt < 4; mt++)
                #pragma unroll
                for (int nt = 0; nt < 2; nt++)
                    acc[mt][nt] = __builtin_amdgcn_mfma_f32_16x16x32_bf16(
                        afr[mt], bfr[nt], acc[mt][nt], 0, 0, 0);
        }
    }

    // bias + leaky + residual (into ACC so both outputs get it)
    #pragma unroll
    for (int nt = 0; nt < 2; nt++) {
        int oc = n0 + nt*16 + l15;
        float bv = bias[oc];
        #pragma unroll
        for (int mt = 0; mt < 4; mt++) {
            int m = mt*16 + quad*4;
            #pragma unroll
            for (int r = 0; r < 4; r++) {
                float v = acc[mt][nt][r] + bv;
                if (leaky) v = (v >= 0.f) ? v : 0.01f * v;
                if (res_cl) v += b2f(res_cl[(size_t)(t0 + m + r) * 128 + oc]);
                acc[mt][nt][r] = v;
            }
        }
    }

    if (out_cl) {
        #pragma unroll
        for (int mt = 0; mt < 4; mt++) {
            int m = mt*16 + quad*4;
            #pragma unroll
            for (int nt = 0; nt < 2; nt++) {
                int oc = n0 + nt*16 + l15;
                #pragma unroll
                for (int r = 0; r < 4; r++)
                    out_cl[(size_t)(t0 + m + r) * 128 + oc] = f2b(acc[mt][nt][r]);
            }
        }
    }

    if (out_f32) {
        __syncthreads();
        float* sT = (float*)&sB[0];      // [128][65] f32 = 33,280 B (sB is 33,280 B)
        #pragma unroll
        for (int mt = 0; mt < 4; mt++) {
            int m = mt*16 + quad*4;
            #pragma unroll
            for (int nt = 0; nt < 2; nt++) {
                int oc = n0 + nt*16 + l15;
                #pragma unroll
                for (int r = 0; r < 4; r++)
                    sT[oc * 65 + m + r] = acc[mt][nt][r];
            }
        }
        __syncthreads();
        int oc = tid >> 1, half = tid & 1;
        size_t obase = ((size_t)b * 256 + oc_base + oc) * SPAT + sp0 + half * 32;
        const float* row = &sT[oc * 65 + half * 32];
        for (int j = 0; j < 32; j++) out_f32[obase + j] = row[j];
    }
}

// ---------------- launch ----------------------------------------------------
extern "C" void kernel_launch(void* const* d_in, const int* in_sizes, int n_in,
                              void* d_out, int out_size, void* d_ws, size_t ws_size,
                              hipStream_t stream)
{
    const float* input  = (const float*)d_in[0];
    const float* n1w    = (const float*)d_in[1];
    const float* n1b    = (const float*)d_in[2];
    const float* n2w    = (const float*)d_in[3];
    const float* n2b    = (const float*)d_in[4];
    const float* wqkv   = (const float*)d_in[5];
    const float* wprojw = (const float*)d_in[6];
    const float* wprojb = (const float*)d_in[7];
    const float* wbias  = (const float*)d_in[8];
    const float* gqkv   = (const float*)d_in[9];
    const float* gprojw = (const float*)d_in[10];
    const float* gprojb = (const float*)d_in[11];
    const float* gbias  = (const float*)d_in[12];
    const float* f1c1w  = (const float*)d_in[13];
    const float* f1c1b  = (const float*)d_in[14];
    const float* f1c2w  = (const float*)d_in[15];
    const float* f1c2b  = (const float*)d_in[16];
    const float* g1c1w  = (const float*)d_in[17];
    const float* g1c1b  = (const float*)d_in[18];
    const float* g1c2w  = (const float*)d_in[19];
    const float* g1c2b  = (const float*)d_in[20];

    char* ws = (char*)d_ws;
    u16* xln   = (u16*)(ws);                    // 25,690,112 B (later: y)
    u16* qkv   = (u16*)(ws + 25690112);         // 77,070,336 B (later: conv bufs)
    u16* attnb = (u16*)(ws + 102760448);        // 25,690,112 B
    u16* xw    = (u16*)(ws + 128450560);        // 25,690,112 B
    u16* y  = xln;
    u16* s1   = qkv;
    u16* s2   = (u16*)(ws + 25690112 + 12845056);
    u16* tb   = (u16*)(ws + 25690112 + 25690112);
    u16* y1cl = (u16*)(ws + 25690112 + 38535168);
    u16* cw0  = (u16*)(ws + 25690112 + 51380224);
    u16* cw1  = cw0 + 442368;
    u16* cw2  = cw1 + 442368;
    u16* cw3  = cw2 + 442368;

    float* outp = (float*)d_out;

    // 1) LN1
    ln1_kernel<<<196, 256, 0, stream>>>(input, n1w, n1b, xln);
    // 2) window qkv
    gemm_mfma_kernel<<<dim3(392, 6), 256, 0, stream>>>(xln, wqkv, nullptr, nullptr, qkv, 768);
    // 3) window attention (MFMA)
    attn_mfma_kernel<<<dim3(512, 4), 256, 0, stream>>>(qkv, wbias, attnb, 0);
    // 4) window proj -> xw
    gemm_mfma_kernel<<<dim3(392, 2), 256, 0, stream>>>(attnb, wprojw, wprojb, nullptr, xw, 256);
    // 5) LN2 -> xln
    ln2_kernel<<<12544, 256, 0, stream>>>(xw, n2w, n2b, xln);
    // 6) grid qkv
    gemm_mfma_kernel<<<dim3(392, 6), 256, 0, stream>>>(xln, gqkv, nullptr, nullptr, qkv, 768);
    // 7) grid attention (MFMA)
    attn_mfma_kernel<<<dim3(512, 4), 256, 0, stream>>>(qkv, gbias, attnb, 1);
    // 8) grid proj + xw residual -> y
    gemm_mfma_kernel<<<dim3(392, 2), 256, 0, stream>>>(attnb, gprojw, gprojb, xw, y, 256);
    // 9) s = input + y -> channel-last halves
    ssplit_cl_kernel<<<784, 256, 0, stream>>>(input, y, s1, s2);
    // 10) conv weight transforms
    convw_kernel<<<1728, 256, 0, stream>>>(f1c1w, cw0);
    convw_kernel<<<1728, 256, 0, stream>>>(f1c2w, cw1);
    convw_kernel<<<1728, 256, 0, stream>>>(g1c1w, cw2);
    convw_kernel<<<1728, 256, 0, stream>>>(g1c2w, cw3);
    // 11) t = leaky(conv(s2, f1c1))
    conv_mfma_kernel<<<784, 256, 0, stream>>>(s2, cw0, f1c1b, nullptr, tb, nullptr, 0, 1);
    // 12) y1 = s1 + conv(t, f1c2) -> d_out[:,0:128] and y1cl
    conv_mfma_kernel<<<784, 256, 0, stream>>>(tb, cw1, f1c2b, s1, y1cl, outp, 0, 0);
    // 13) t = leaky(conv(y1, g1c1))
    conv_mfma_kernel<<<784, 256, 0, stream>>>(y1cl, cw2, g1c1b, nullptr, tb, nullptr, 0, 1);
    // 14) y2 = s2 + conv(t, g1c2) -> d_out[:,128:256]
    conv_mfma_kernel<<<784, 256, 0, stream>>>(tb, cw3, g1c2b, s2, nullptr, outp, 128, 0);
}

// Round 8
// 854.101 us; speedup vs baseline: 1.4660x; 1.1374x over previous
//
#include <hip/hip_runtime.h>
#include <stdint.h>

// MixBlock3D: B=2 C=256 D=8 H=56 W=56, GWS=(2,7,7). I/O f32, intermediates bf16.
// Round 8: conv — B fragments streamed from fragment-linear GLOBAL weights
// (coalesced 1KB wave loads, L2-hot), A in lane-linear conflict-free LDS with
// register double-buffer prefetch; one barrier per tap.

typedef unsigned short u16;
typedef __attribute__((ext_vector_type(8))) short short8;  // 8 bf16 = 4 VGPR
typedef __attribute__((ext_vector_type(4))) float f32x4;   // 4 fp32 acc

#define TOK   50176
#define CH    256
#define SPAT  25088
#define PLANE 3136

__device__ __forceinline__ float b2f(u16 u) {
    union { uint32_t i; float f; } v; v.i = ((uint32_t)u) << 16; return v.f;
}
__device__ __forceinline__ u16 f2b(float f) {
    union { float f; uint32_t i; } v; v.f = f;
    uint32_t i = v.i;
    uint32_t r = i + 0x7FFFu + ((i >> 16) & 1u);
    return (u16)(r >> 16);
}

// ---------------- LN1: NCDHW f32 -> token-major (t, c) bf16 -----------------
__global__ __launch_bounds__(256) void ln1_kernel(
    const float* __restrict__ x, const float* __restrict__ w,
    const float* __restrict__ bsh, u16* __restrict__ out)
{
    int t = blockIdx.x * 256 + threadIdx.x;
    int b = t / SPAT, sp = t % SPAT;
    const float* px = x + (size_t)b * CH * SPAT + sp;
    float s = 0.f, ss = 0.f;
    for (int c = 0; c < CH; c++) { float v = px[(size_t)c * SPAT]; s += v; ss += v * v; }
    float mean = s * (1.0f / CH);
    float var  = ss * (1.0f / CH) - mean * mean;
    float rstd = rsqrtf(var + 1e-5f);
    u16* po = out + (size_t)t * CH;
    for (int c = 0; c < CH; c++) {
        float v = (px[(size_t)c * SPAT] - mean) * rstd * w[c] + bsh[c];
        po[c] = f2b(v);
    }
}

// ---------------- LN2: token-major bf16 -> token-major bf16 -----------------
__global__ __launch_bounds__(256) void ln2_kernel(
    const u16* __restrict__ x, const float* __restrict__ w,
    const float* __restrict__ bsh, u16* __restrict__ out)
{
    int wave = threadIdx.x >> 6, lane = threadIdx.x & 63;
    int t = blockIdx.x * 4 + wave;
    const u16* px = x + (size_t)t * CH + lane * 4;
    ushort4 v4 = *(const ushort4*)px;
    float v0 = b2f(v4.x), v1 = b2f(v4.y), v2 = b2f(v4.z), v3 = b2f(v4.w);
    float s = v0 + v1 + v2 + v3;
    float ss = v0*v0 + v1*v1 + v2*v2 + v3*v3;
    for (int o = 32; o > 0; o >>= 1) {
        s  += __shfl_xor(s,  o, 64);
        ss += __shfl_xor(ss, o, 64);
    }
    float mean = s * (1.0f / CH);
    float rstd = rsqrtf(ss * (1.0f / CH) - mean * mean + 1e-5f);
    float4 w4 = *(const float4*)(w + lane * 4);
    float4 b4 = *(const float4*)(bsh + lane * 4);
    ushort4 o4;
    o4.x = f2b((v0 - mean) * rstd * w4.x + b4.x);
    o4.y = f2b((v1 - mean) * rstd * w4.y + b4.y);
    o4.z = f2b((v2 - mean) * rstd * w4.z + b4.z);
    o4.w = f2b((v3 - mean) * rstd * w4.w + b4.w);
    *(ushort4*)(out + (size_t)t * CH + lane * 4) = o4;
}

// ---- MFMA GEMM: C[M,Nout slice] = A[M,256](bf16) @ B[N,256]^T(f32 weights) ----
__global__ __launch_bounds__(256) void gemm_mfma_kernel(
    const u16* __restrict__ A, const float* __restrict__ B,
    const float* __restrict__ bias, const u16* __restrict__ res,
    u16* __restrict__ C, int Nout)
{
    __shared__ u16 sAg[128][72];
    __shared__ u16 sBg[128][72];
    int tid = threadIdx.x;
    int m0 = blockIdx.x * 128, n0g = blockIdx.y * 128;
    int lane = tid & 63, wv = tid >> 6;
    int quad = lane >> 4, l15 = lane & 15;
    int mw = (wv & 1) * 64, nw = (wv >> 1) * 64;

    f32x4 zz = {0.f, 0.f, 0.f, 0.f};
    f32x4 acc[4][4];
    #pragma unroll
    for (int i = 0; i < 4; i++)
        #pragma unroll
        for (int j = 0; j < 4; j++) acc[i][j] = zz;

    for (int kc = 0; kc < 256; kc += 64) {
        __syncthreads();
        #pragma unroll
        for (int i = 0; i < 4; i++) {
            int unit = tid + i * 256;
            int row = unit >> 3, k8 = (unit & 7) << 3;
            *(uint4*)&sAg[row][k8] = *(const uint4*)(A + (size_t)(m0 + row) * 256 + kc + k8);
        }
        #pragma unroll
        for (int i = 0; i < 8; i++) {
            int unit = tid + i * 256;
            int row = unit >> 4, k4 = (unit & 15) << 2;
            float4 v = *(const float4*)(B + (size_t)(n0g + row) * 256 + kc + k4);
            ushort4 p;
            p.x = f2b(v.x); p.y = f2b(v.y); p.z = f2b(v.z); p.w = f2b(v.w);
            *(ushort4*)&sBg[row][k4] = p;
        }
        __syncthreads();
        #pragma unroll
        for (int kk = 0; kk < 2; kk++) {
            short8 afr[4], bfr[4];
            #pragma unroll
            for (int mt = 0; mt < 4; mt++)
                afr[mt] = *(const short8*)&sAg[mw + mt*16 + l15][kk*32 + quad*8];
            #pragma unroll
            for (int nt = 0; nt < 4; nt++)
                bfr[nt] = *(const short8*)&sBg[nw + nt*16 + l15][kk*32 + quad*8];
            #pragma unroll
            for (int mt = 0; mt < 4; mt++)
                #pragma unroll
                for (int nt = 0; nt < 4; nt++)
                    acc[mt][nt] = __builtin_amdgcn_mfma_f32_16x16x32_bf16(
                        afr[mt], bfr[nt], acc[mt][nt], 0, 0, 0);
        }
    }

    #pragma unroll
    for (int nt = 0; nt < 4; nt++) {
        int n = n0g + nw + nt*16 + l15;
        float bv = bias ? bias[n] : 0.f;
        #pragma unroll
        for (int mt = 0; mt < 4; mt++) {
            int m = m0 + mw + mt*16 + quad*4;
            #pragma unroll
            for (int r = 0; r < 4; r++) {
                float v = acc[mt][nt][r] + bv;
                size_t off = (size_t)(m + r) * Nout + n;
                if (res) v += b2f(res[off]);
                C[off] = f2b(v);
            }
        }
    }
}

// ---------------- MFMA Attention: one block per (group, head) ---------------
__global__ __launch_bounds__(256) void attn_mfma_kernel(
    const u16* __restrict__ qkv, const float* __restrict__ btab,
    u16* __restrict__ outp, int mode)
{
    __shared__ u16 sKV[8704];        // K [112][72] then V^T [64][136]
    __shared__ u16 sS[112][136];
    __shared__ float sBias[507];
    __shared__ int sTok[112];
    __shared__ int sEnc[112];
    __shared__ float sInv[112];

    int g = blockIdx.x, head = blockIdx.y, tid = threadIdx.x;
    int b  = g >> 8;
    int gd = (g >> 6) & 3, gh = (g >> 3) & 7, gw = g & 7;

    int lane = tid & 63, wv = tid >> 6;
    int quad = lane >> 4, l15 = lane & 15;
    int mts[2] = {wv, wv + 4};

    if (tid < 112) {
        int t = tid;
        int i = t / 49, r = t % 49, j = r / 7, k = r % 7;
        sEnc[tid] = i * 169 + j * 13 + k;
        int tokv = 0;
        if (t < 98) {
            int d, h, w;
            if (mode == 0) { d = gd*2 + i; h = gh*7 + j; w = gw*7 + k; }
            else           { d = i*4 + gd; h = j*8 + gh; w = k*8 + gw; }
            tokv = ((b*8 + d)*56 + h)*56 + w;
        }
        sTok[tid] = tokv;
    }
    for (int idx = tid; idx < 507; idx += 256) sBias[idx] = btab[idx * 4 + head];
    __syncthreads();

    for (int idx = tid; idx < 112 * 8; idx += 256) {
        int row = idx >> 3, c8 = (idx & 7) << 3;
        uint4 v = {0u, 0u, 0u, 0u};
        if (row < 98)
            v = *(const uint4*)(qkv + (size_t)sTok[row] * 768 + 256 + head * 64 + c8);
        *(uint4*)&sKV[row * 72 + c8] = v;
    }
    __syncthreads();

    short8 qf[2][2];
    #pragma unroll
    for (int mi = 0; mi < 2; mi++) {
        int mt = mts[mi];
        #pragma unroll
        for (int ks = 0; ks < 2; ks++) {
            short8 v;
            #pragma unroll
            for (int j = 0; j < 8; j++) v[j] = 0;
            int row = mt * 16 + l15;
            if (mt < 7 && row < 98)
                v = *(const short8*)(qkv + (size_t)sTok[row] * 768 + head * 64 + ks * 32 + quad * 8);
            qf[mi][ks] = v;
        }
    }

    f32x4 zz = {0.f, 0.f, 0.f, 0.f};
    #pragma unroll
    for (int mi = 0; mi < 2; mi++) {
        int mt = mts[mi];
        if (mt >= 7) continue;
        for (int nt = 0; nt < 7; nt++) {
            f32x4 acc = zz;
            acc = __builtin_amdgcn_mfma_f32_16x16x32_bf16(
                qf[mi][0], *(const short8*)&sKV[(nt*16 + l15) * 72 + quad*8], acc, 0, 0, 0);
            acc = __builtin_amdgcn_mfma_f32_16x16x32_bf16(
                qf[mi][1], *(const short8*)&sKV[(nt*16 + l15) * 72 + 32 + quad*8], acc, 0, 0, 0);
            int n = nt * 16 + l15;
            int en = (n < 98) ? sEnc[n] : 0;
            #pragma unroll
            for (int r = 0; r < 4; r++) {
                int m = mt * 16 + quad * 4 + r;
                float v;
                if (n < 98) {
                    int em = sEnc[m < 98 ? m : 97];
                    v = acc[r] * 0.125f + sBias[em - en + 253];
                } else v = -1e30f;
                sS[m][n] = f2b(v);
            }
        }
    }
    __syncthreads();

    for (int idx = tid; idx < 64 * 30; idx += 256) {
        int c = idx / 30, t = 98 + idx % 30;
        sKV[c * 136 + t] = 0;
    }
    for (int idx = tid; idx < 98 * 8; idx += 256) {
        int tok = idx >> 3, c8 = (idx & 7) << 3;
        uint4 v = *(const uint4*)(qkv + (size_t)sTok[tok] * 768 + 512 + head * 64 + c8);
        const u16* pv = (const u16*)&v;
        #pragma unroll
        for (int j = 0; j < 8; j++) sKV[(c8 + j) * 136 + tok] = pv[j];
    }

    {
        int row = tid >> 1, half = tid & 1;
        if (row < 112) {
            #pragma unroll
            for (int j = 0; j < 8; j++) sS[row][112 + half * 8 + j] = 0;
        }
        if (row < 98) {
            int c0 = half * 49;
            float mx = -1e30f;
            for (int j = 0; j < 49; j++) mx = fmaxf(mx, b2f(sS[row][c0 + j]));
            mx = fmaxf(mx, __shfl_xor(mx, 1, 64));
            float sum = 0.f;
            for (int j = 0; j < 49; j++) {
                float e = __expf(b2f(sS[row][c0 + j]) - mx);
                sum += e;
                sS[row][c0 + j] = f2b(e);
            }
            sum += __shfl_xor(sum, 1, 64);
            if (half == 0) sInv[row] = 1.0f / sum;
        }
    }
    __syncthreads();

    f32x4 po[2][4];
    #pragma unroll
    for (int mi = 0; mi < 2; mi++)
        #pragma unroll
        for (int nt = 0; nt < 4; nt++) po[mi][nt] = zz;

    #pragma unroll
    for (int mi = 0; mi < 2; mi++) {
        int mt = mts[mi];
        if (mt >= 7) continue;
        for (int ks = 0; ks < 4; ks++) {
            short8 ap = *(const short8*)&sS[mt*16 + l15][ks*32 + quad*8];
            #pragma unroll
            for (int nt = 0; nt < 4; nt++) {
                short8 bv = *(const short8*)&sKV[(nt*16 + l15) * 136 + ks*32 + quad*8];
                po[mi][nt] = __builtin_amdgcn_mfma_f32_16x16x32_bf16(ap, bv, po[mi][nt], 0, 0, 0);
            }
        }
    }

    #pragma unroll
    for (int mi = 0; mi < 2; mi++) {
        int mt = mts[mi];
        if (mt >= 7) continue;
        #pragma unroll
        for (int r = 0; r < 4; r++) {
            int m = mt * 16 + quad * 4 + r;
            if (m >= 98) continue;
            float inv = sInv[m];
            u16* dst = outp + (size_t)sTok[m] * 256 + head * 64 + l15;
            #pragma unroll
            for (int nt = 0; nt < 4; nt++)
                dst[nt * 16] = f2b(po[mi][nt][r] * inv);
        }
    }
}

// ---- s = input(f32 NCDHW) + y(bf16 token-major) -> s1/s2 channel-last bf16 --
__global__ __launch_bounds__(256) void ssplit_cl_kernel(
    const float* __restrict__ inp, const u16* __restrict__ y,
    u16* __restrict__ s1, u16* __restrict__ s2)
{
    __shared__ float sT[64][65];
    int t0 = blockIdx.x * 64;
    int b = t0 / SPAT, sp0 = t0 % SPAT;
    int tid = threadIdx.x;
    for (int cg = 0; cg < 4; cg++) {
        __syncthreads();
        #pragma unroll
        for (int i = 0; i < 16; i++) {
            int unit = tid + i * 256;
            int cl = unit >> 6, spl = unit & 63;
            sT[spl][cl] = inp[((size_t)(b * 256 + cg * 64 + cl)) * SPAT + sp0 + spl];
        }
        __syncthreads();
        int spl = tid >> 2, c16 = (tid & 3) * 16;
        int tok = t0 + spl;
        const u16* yp = y + (size_t)tok * 256 + cg * 64 + c16;
        int cbase = cg * 64 + c16;
        u16* dst = (cbase < 128) ? (s1 + (size_t)tok * 128 + cbase)
                                 : (s2 + (size_t)tok * 128 + cbase - 128);
        #pragma unroll
        for (int j = 0; j < 16; j++) {
            float v = sT[spl][c16 + j] + b2f(yp[j]);
            dst[j] = f2b(v);
        }
    }
}

// ---- conv weight transform: f32 [oc][ic][27] -> bf16 fragment-linear -------
// dst index e = ((((tap*4+kk)*8+nt)*4+quad)*16+l15)*8 + j
// with oc = nt*16+l15, ic = kk*32+quad*8+j.
__global__ __launch_bounds__(256) void convw_kernel(
    const float* __restrict__ w, u16* __restrict__ o)
{
    int e = blockIdx.x * 256 + threadIdx.x;   // 442368 total
    int tap = e >> 14;
    int r = e & 16383;
    int kk = r >> 12;
    int nt = (r >> 9) & 7;
    int quad = (r >> 7) & 3;
    int l15 = (r >> 3) & 15;
    int j = r & 7;
    int oc = nt * 16 + l15;
    int ic = kk * 32 + quad * 8 + j;
    o[e] = f2b(w[(size_t)(oc * 128 + ic) * 27 + tap]);
}

// ---- MFMA conv 3x3x3 128->128: A in lane-linear dbuf LDS, B from global ----
// block: 64 tokens x 128 oc, 4 waves (wave = 64 tok x 32 oc).
// A LDS layout: buf[2][ (kk*4+mt)*512 + lane*8 ]  (conflict-free b128 r/w).
// B: fragment-linear global (convw_kernel), 1KB coalesced wave loads, L2-hot.
__global__ __launch_bounds__(256, 3) void conv_mfma_kernel(
    const u16* __restrict__ in_cl,   // [B*SPAT][128] bf16
    const u16* __restrict__ wtf,     // fragment-linear weights (442368)
    const float* __restrict__ bias,  // [128] f32
    const u16* __restrict__ res_cl,  // nullable [tok][128] bf16 (added to acc)
    u16* __restrict__ out_cl,        // nullable [tok][128] bf16
    float* __restrict__ out_f32,     // nullable NCDHW f32 (256-ch layout)
    int oc_base, int leaky)
{
    __shared__ u16 sA[2][8192];      // 32,768 B  (aliased as f32 sT in epilogue)
    __shared__ int sD[64], sHH[64], sWW[64];

    int tid = threadIdx.x;
    int t0 = blockIdx.x * 64;
    int b = t0 / SPAT, sp0 = t0 % SPAT;

    if (tid < 64) {
        int sp = sp0 + tid;
        int d = sp / PLANE, r = sp % PLANE;
        sD[tid] = d; sHH[tid] = r / 56; sWW[tid] = r % 56;
    }
    __syncthreads();

    int lane = tid & 63, wv = tid >> 6;
    int quad = lane >> 4, l15 = lane & 15;
    int n0 = wv * 32;

    // staging unit decomposition (4 units per thread)
    int u_l15[4], u_kq[4], u_m[4];
    #pragma unroll
    for (int i = 0; i < 4; i++) {
        int unit = tid + i * 256;
        int mtkk = unit >> 6;               // kk*4 + mt
        int mt = mtkk & 3;
        u_m[i]  = mt * 16 + (unit & 15);    // token row in tile
        u_kq[i] = ((mtkk >> 2) * 32 + ((unit >> 4) & 3) * 8);  // ic offset
        u_l15[i] = unit;                    // LDS offset = unit*8
    }

    f32x4 zz = {0.f, 0.f, 0.f, 0.f};
    f32x4 acc[4][2];
    #pragma unroll
    for (int i = 0; i < 4; i++) { acc[i][0] = zz; acc[i][1] = zz; }

    uint4 pre[4];

    // stage helper expressed inline: loads tap's A into pre[]
    #define STAGE_REGS(TAP)                                                    \
    {                                                                          \
        int kd = (TAP) / 9 - 1, kh = ((TAP) / 3) % 3 - 1, kw = (TAP) % 3 - 1;  \
        _Pragma("unroll")                                                      \
        for (int i = 0; i < 4; i++) {                                          \
            int m = u_m[i];                                                    \
            int dd = sD[m] + kd, hh = sHH[m] + kh, ww = sWW[m] + kw;           \
            uint4 v = {0u, 0u, 0u, 0u};                                        \
            if ((unsigned)dd < 8u && (unsigned)hh < 56u && (unsigned)ww < 56u) \
                v = *(const uint4*)(in_cl +                                    \
                    ((size_t)(b * 8 + dd) * PLANE + hh * 56 + ww) * 128 + u_kq[i]); \
            pre[i] = v;                                                        \
        }                                                                      \
    }

    STAGE_REGS(0);
    #pragma unroll
    for (int i = 0; i < 4; i++) *(uint4*)&sA[0][u_l15[i] * 8] = pre[i];
    __syncthreads();

    for (int tap = 0; tap < 27; tap++) {
        int cur = tap & 1;
        if (tap < 26) STAGE_REGS(tap + 1);

        const u16* wb = wtf + tap * 16384;
        #pragma unroll
        for (int kk = 0; kk < 4; kk++) {
            short8 afr[4], bfr[2];
            #pragma unroll
            for (int mt = 0; mt < 4; mt++)
                afr[mt] = *(const short8*)&sA[cur][((kk*4 + mt)*64 + lane) * 8];
            #pragma unroll
            for (int nt = 0; nt < 2; nt++)
                bfr[nt] = *(const short8*)(wb + ((kk*8 + n0/16 + nt)*64 + lane) * 8);
            #pragma unroll
            for (int mt = 0; mt < 4; mt++)
                #pragma unroll
                for (int nt = 0; nt < 2; nt++)
                    acc[mt][nt] = __builtin_amdgcn_mfma_f32_16x16x32_bf16(
                        afr[mt], bfr[nt], acc[mt][nt], 0, 0, 0);
        }

        if (tap < 26) {
            #pragma unroll
            for (int i = 0; i < 4; i++) *(uint4*)&sA[cur ^ 1][u_l15[i] * 8] = pre[i];
        }
        __syncthreads();
    }
    #undef STAGE_REGS

    // bias + leaky + residual (into ACC so both outputs get it)
    #pragma unroll
    for (int nt = 0; nt < 2; nt++) {
        int oc = n0 + nt*16 + l15;
        float bv = bias[oc];
        #pragma unroll
        for (int mt = 0; mt < 4; mt++) {
            int m = mt*16 + quad*4;
            #pragma unroll
            for (int r = 0; r < 4; r++) {
                float v = acc[mt][nt][r] + bv;
                if (leaky) v = (v >= 0.f) ? v : 0.01f * v;
                if (res_cl) v += b2f(res_cl[(size_t)(t0 + m + r) * 128 + oc]);
                acc[mt][nt][r] = v;
            }
        }
    }

    if (out_cl) {
        #pragma unroll
        for (int mt = 0; mt < 4; mt++) {
            int m = mt*16 + quad*4;
            #pragma unroll
            for (int nt = 0; nt < 2; nt++) {
                int oc = n0 + nt*16 + l15;
                #pragma unroll
                for (int r = 0; r < 4; r++)
                    out_cl[(size_t)(t0 + m + r) * 128 + oc] = f2b(acc[mt][nt][r]);
            }
        }
    }

    if (out_f32) {
        __syncthreads();
        float* sT = (float*)&sA[0][0];   // [128][64] f32 = 32,768 B
        // write columns in two half-passes to fit 32KB: oc-major stride 64
        #pragma unroll
        for (int mt = 0; mt < 4; mt++) {
            int m = mt*16 + quad*4;
            #pragma unroll
            for (int nt = 0; nt < 2; nt++) {
                int oc = n0 + nt*16 + l15;
                #pragma unroll
                for (int r = 0; r < 4; r++)
                    sT[oc * 64 + ((m + r + oc) & 63)] = acc[mt][nt][r];  // skewed
            }
        }
        __syncthreads();
        int oc = tid >> 1, half = tid & 1;
        size_t obase = ((size_t)b * 256 + oc_base + oc) * SPAT + sp0 + half * 32;
        const float* row = &sT[oc * 64];
        for (int j = 0; j < 32; j++) {
            int m = half * 32 + j;
            out_f32[obase + j] = row[(m + oc) & 63];   // unskew
        }
    }
}

// ---------------- launch ----------------------------------------------------
extern "C" void kernel_launch(void* const* d_in, const int* in_sizes, int n_in,
                              void* d_out, int out_size, void* d_ws, size_t ws_size,
                              hipStream_t stream)
{
    const float* input  = (const float*)d_in[0];
    const float* n1w    = (const float*)d_in[1];
    const float* n1b    = (const float*)d_in[2];
    const float* n2w    = (const float*)d_in[3];
    const float* n2b    = (const float*)d_in[4];
    const float* wqkv   = (const float*)d_in[5];
    const float* wprojw = (const float*)d_in[6];
    const float* wprojb = (const float*)d_in[7];
    const float* wbias  = (const float*)d_in[8];
    const float* gqkv   = (const float*)d_in[9];
    const float* gprojw = (const float*)d_in[10];
    const float* gprojb = (const float*)d_in[11];
    const float* gbias  = (const float*)d_in[12];
    const float* f1c1w  = (const float*)d_in[13];
    const float* f1c1b  = (const float*)d_in[14];
    const float* f1c2w  = (const float*)d_in[15];
    const float* f1c2b  = (const float*)d_in[16];
    const float* g1c1w  = (const float*)d_in[17];
    const float* g1c1b  = (const float*)d_in[18];
    const float* g1c2w  = (const float*)d_in[19];
    const float* g1c2b  = (const float*)d_in[20];

    char* ws = (char*)d_ws;
    u16* xln   = (u16*)(ws);                    // 25,690,112 B (later: y)
    u16* qkv   = (u16*)(ws + 25690112);         // 77,070,336 B (later: conv bufs)
    u16* attnb = (u16*)(ws + 102760448);        // 25,690,112 B
    u16* xw    = (u16*)(ws + 128450560);        // 25,690,112 B
    u16* y  = xln;
    u16* s1   = qkv;
    u16* s2   = (u16*)(ws + 25690112 + 12845056);
    u16* tb   = (u16*)(ws + 25690112 + 25690112);
    u16* y1cl = (u16*)(ws + 25690112 + 38535168);
    u16* cw0  = (u16*)(ws + 25690112 + 51380224);
    u16* cw1  = cw0 + 442368;
    u16* cw2  = cw1 + 442368;
    u16* cw3  = cw2 + 442368;

    float* outp = (float*)d_out;

    // 1) LN1
    ln1_kernel<<<196, 256, 0, stream>>>(input, n1w, n1b, xln);
    // 2) window qkv
    gemm_mfma_kernel<<<dim3(392, 6), 256, 0, stream>>>(xln, wqkv, nullptr, nullptr, qkv, 768);
    // 3) window attention (MFMA)
    attn_mfma_kernel<<<dim3(512, 4), 256, 0, stream>>>(qkv, wbias, attnb, 0);
    // 4) window proj -> xw
    gemm_mfma_kernel<<<dim3(392, 2), 256, 0, stream>>>(attnb, wprojw, wprojb, nullptr, xw, 256);
    // 5) LN2 -> xln
    ln2_kernel<<<12544, 256, 0, stream>>>(xw, n2w, n2b, xln);
    // 6) grid qkv
    gemm_mfma_kernel<<<dim3(392, 6), 256, 0, stream>>>(xln, gqkv, nullptr, nullptr, qkv, 768);
    // 7) grid attention (MFMA)
    attn_mfma_kernel<<<dim3(512, 4), 256, 0, stream>>>(qkv, gbias, attnb, 1);
    // 8) grid proj + xw residual -> y
    gemm_mfma_kernel<<<dim3(392, 2), 256, 0, stream>>>(attnb, gprojw, gprojb, xw, y, 256);
    // 9) s = input + y -> channel-last halves
    ssplit_cl_kernel<<<784, 256, 0, stream>>>(input, y, s1, s2);
    // 10) conv weight transforms (fragment-linear)
    convw_kernel<<<1728, 256, 0, stream>>>(f1c1w, cw0);
    convw_kernel<<<1728, 256, 0, stream>>>(f1c2w, cw1);
    convw_kernel<<<1728, 256, 0, stream>>>(g1c1w, cw2);
    convw_kernel<<<1728, 256, 0, stream>>>(g1c2w, cw3);
    // 11) t = leaky(conv(s2, f1c1))
    conv_mfma_kernel<<<784, 256, 0, stream>>>(s2, cw0, f1c1b, nullptr, tb, nullptr, 0, 1);
    // 12) y1 = s1 + conv(t, f1c2) -> d_out[:,0:128] and y1cl
    conv_mfma_kernel<<<784, 256, 0, stream>>>(tb, cw1, f1c2b, s1, y1cl, outp, 0, 0);
    // 13) t = leaky(conv(y1, g1c1))
    conv_mfma_kernel<<<784, 256, 0, stream>>>(y1cl, cw2, g1c1b, nullptr, tb, nullptr, 0, 1);
    // 14) y2 = s2 + conv(t, g1c2) -> d_out[:,128:256]
    conv_mfma_kernel<<<784, 256, 0, stream>>>(tb, cw3, g1c2b, s2, nullptr, outp, 128, 0);
}